// Round 7
// baseline (71.313 us; speedup 1.0000x reference)
//
#include <hip/hip_runtime.h>

typedef float f32x4 __attribute__((ext_vector_type(4)));

// Problem constants (fixed by reference setup_inputs)
constexpr int Bc = 8;
constexpr int Sc = 4096;
constexpr int Dc = 2048;
constexpr int Ec = 16;
constexpr int S_PER_BLK = 8;             // s-values per block
constexpr int TOK_PER_BLK = Bc * S_PER_BLK;  // 64 tokens (all 8 b's x 8 s)
constexpr int NBLK = Sc / S_PER_BLK;     // 512 blocks (2 per CU)
constexpr float EPS = 1e-6f;
constexpr float CAPACITY = 8.0f;         // int(1.0 * B)

// ---------------------------------------------------------------------------
// Fully fused SwitchGate kernel (one launch).
//   Block owns s in [8*bid, 8*bid+8) for ALL 8 batch rows -> cross-B
//   denominator is block-local. Token-local index t = b*8 + s_loc.
//
//   Phase 1: 8 waves = 8 DISJOINT D-eighths (256 floats, 1 float4/lane).
//     Each wave computes ALL 16 experts for its slice (W = 16 f32x4 = 64
//     VGPR/lane). X requested exactly once block-wide, one dwordx4 per
//     wave per token (1 KB/instr, fully coalesced) -> load stream is
//     copy-µbench-shaped. Depth-4 register pipeline (no nt loads).
//     Value-merging butterfly: 17 shfl reduces 16 accs; lane l&15 ends
//     holding expert (l&15); lanes 0..15 write plds[w][t][lane].
//   Phase 2: 8 thr/token: combine eighths + bias, softmax, top-8 mask
//     (rank count, ties->lower idx = lax.top_k), masked scores -> LDS.
//   Phase 3: cross-B normalize, coalesced float2 stores to d_out.
// ---------------------------------------------------------------------------
__global__ __launch_bounds__(512, 4) void k_switchgate(
    const float* __restrict__ X, const float* __restrict__ W,
    const float* __restrict__ bias, float* __restrict__ out) {
  __shared__ float plds[8][TOK_PER_BLK][20];   // 40 KB partial logits
  __shared__ float masked[TOK_PER_BLK][18];    // 4.5 KB masked scores
  __shared__ float bias_lds[Ec];

  const int tid  = threadIdx.x;
  const int w    = tid >> 6;    // wave 0..7 = D-eighth
  const int lane = tid & 63;

  if (tid < Ec) bias_lds[tid] = bias[tid];

  // W fragments: wreg[j] covers expert j, d = w*256 + lane*4 + {0..3}
  f32x4 wreg[16];
#pragma unroll
  for (int j = 0; j < 16; ++j) {
    wreg[j] = *reinterpret_cast<const f32x4*>(
        W + (size_t)j * Dc + w * 256 + lane * 4);
  }

  const int s0 = blockIdx.x * S_PER_BLK;
  const float* xbase = X + (size_t)s0 * Dc + w * 256 + lane * 4;

  f32x4 xa, xb, xc, xd;

#define LOAD_BUF(buf, t)                                                      \
  {                                                                           \
    const float* p_ = xbase + (size_t)((t) >> 3) * (Sc * (size_t)Dc) +        \
                      (size_t)((t) & 7) * Dc;                                 \
    buf = *reinterpret_cast<const f32x4*>(p_);                                \
  }

#define COMPUTE_STORE(buf, t)                                                 \
  {                                                                           \
    float acc[16];                                                            \
    _Pragma("unroll") for (int j_ = 0; j_ < 16; ++j_) acc[j_] = 0.f;          \
    _Pragma("unroll") for (int c_ = 0; c_ < 4; ++c_) {                        \
      _Pragma("unroll") for (int j_ = 0; j_ < 16; ++j_) {                     \
        acc[j_] = fmaf(buf[c_], wreg[j_][c_], acc[j_]);                       \
      }                                                                       \
    }                                                                         \
    /* value-merging butterfly: 17 shfl; lane l -> expert (l&15) */           \
    const bool o1 = (lane & 1) != 0;                                          \
    float m1[8];                                                              \
    _Pragma("unroll") for (int k_ = 0; k_ < 8; ++k_) {                        \
      float s_ = o1 ? acc[2 * k_] : acc[2 * k_ + 1];                          \
      float r_ = __shfl_xor(s_, 1, 64);                                       \
      m1[k_] = o1 ? (acc[2 * k_ + 1] + r_) : (acc[2 * k_] + r_);              \
    }                                                                         \
    const bool o2 = (lane & 2) != 0;                                          \
    float m2[4];                                                              \
    _Pragma("unroll") for (int k_ = 0; k_ < 4; ++k_) {                        \
      float s_ = o2 ? m1[2 * k_] : m1[2 * k_ + 1];                            \
      float r_ = __shfl_xor(s_, 2, 64);                                       \
      m2[k_] = o2 ? (m1[2 * k_ + 1] + r_) : (m1[2 * k_] + r_);                \
    }                                                                         \
    const bool o4 = (lane & 4) != 0;                                          \
    float m4[2];                                                              \
    _Pragma("unroll") for (int k_ = 0; k_ < 2; ++k_) {                        \
      float s_ = o4 ? m2[2 * k_] : m2[2 * k_ + 1];                            \
      float r_ = __shfl_xor(s_, 4, 64);                                       \
      m4[k_] = o4 ? (m2[2 * k_ + 1] + r_) : (m2[2 * k_] + r_);                \
    }                                                                         \
    const bool o8 = (lane & 8) != 0;                                          \
    float mv;                                                                 \
    { float s_ = o8 ? m4[0] : m4[1];                                          \
      float r_ = __shfl_xor(s_, 8, 64);                                       \
      mv = o8 ? (m4[1] + r_) : (m4[0] + r_); }                                \
    mv += __shfl_xor(mv, 16, 64);                                             \
    mv += __shfl_xor(mv, 32, 64);                                             \
    if (lane < 16) plds[w][t][lane] = mv;                                     \
  }

  // prologue: fill the 4-deep pipeline
  LOAD_BUF(xa, 0)
  LOAD_BUF(xb, 1)
  LOAD_BUF(xc, 2)
  LOAD_BUF(xd, 3)

#pragma unroll 1
  for (int t = 0; t < TOK_PER_BLK - 8; t += 4) {
    COMPUTE_STORE(xa, t)
    LOAD_BUF(xa, t + 4)
    COMPUTE_STORE(xb, t + 1)
    LOAD_BUF(xb, t + 5)
    COMPUTE_STORE(xc, t + 2)
    LOAD_BUF(xc, t + 6)
    COMPUTE_STORE(xd, t + 3)
    LOAD_BUF(xd, t + 7)
  }
  // epilogue: tokens 56..63
  COMPUTE_STORE(xa, 56)
  LOAD_BUF(xa, 60)
  COMPUTE_STORE(xb, 57)
  LOAD_BUF(xb, 61)
  COMPUTE_STORE(xc, 58)
  LOAD_BUF(xc, 62)
  COMPUTE_STORE(xd, 59)
  LOAD_BUF(xd, 63)
  COMPUTE_STORE(xa, 60)
  COMPUTE_STORE(xb, 61)
  COMPUTE_STORE(xc, 62)
  COMPUTE_STORE(xd, 63)

#undef LOAD_BUF
#undef COMPUTE_STORE

  __syncthreads();

  // ---- Phase 2: gate. 8 threads per token, each owns 2 experts. ----
  {
    const int t = tid >> 3;   // token-local 0..63 (= b*8 + s_loc)
    const int j = tid & 7;    // expert-pair index

    float l[16];
#pragma unroll
    for (int i = 0; i < 16; ++i) l[i] = bias_lds[i];
#pragma unroll
    for (int u = 0; u < 8; ++u) {
#pragma unroll
      for (int blk = 0; blk < 4; ++blk) {
        const f32x4 v = *reinterpret_cast<const f32x4*>(&plds[u][t][blk * 4]);
#pragma unroll
        for (int c = 0; c < 4; ++c) l[blk * 4 + c] += v[c];
      }
    }

    float m = l[0];
#pragma unroll
    for (int i = 1; i < 16; ++i) m = fmaxf(m, l[i]);

    float ex[16];
    float Z = 0.f;
#pragma unroll
    for (int i = 0; i < 16; ++i) {
      ex[i] = __expf(l[i] - m);
      Z += ex[i];
    }
    const float invZ = 1.0f / Z;

    // top-8 mask via rank count (ties -> lower index, matches lax.top_k)
    const int i0 = 2 * j;
    int c0 = 0, c1 = 0;
#pragma unroll
    for (int k = 0; k < 16; ++k) {
      c0 += (l[k] > l[i0]) || ((l[k] == l[i0]) && (k < i0));
      c1 += (l[k] > l[i0 + 1]) || ((l[k] == l[i0 + 1]) && (k < i0 + 1));
    }
    float2 r;
    r.x = (c0 < 8) ? ex[i0] * invZ : 0.0f;
    r.y = (c1 < 8) ? ex[i0 + 1] * invZ : 0.0f;
    *reinterpret_cast<float2*>(&masked[t][i0]) = r;
  }

  __syncthreads();

  // ---- Phase 3: cross-B normalize + store. ----
  // thread tid = b*64 + s_loc*8 + j  (b = wave id -> coalesced 512B/wave)
  {
    const int b     = tid >> 6;
    const int s_loc = (tid >> 3) & 7;
    const int j     = tid & 7;
    const int i0    = 2 * j;

    float2 den = make_float2(EPS, EPS);
#pragma unroll
    for (int bp = 0; bp < 8; ++bp) {
      const float2 v = *reinterpret_cast<const float2*>(&masked[bp * 8 + s_loc][i0]);
      den.x += v.x;
      den.y += v.y;
    }
    const float2 mv = *reinterpret_cast<const float2*>(&masked[b * 8 + s_loc][i0]);
    float2 r;
    r.x = mv.x * CAPACITY / den.x;
    r.y = mv.y * CAPACITY / den.y;
    *reinterpret_cast<float2*>(
        out + ((size_t)b * Sc + s0 + s_loc) * Ec + i0) = r;
  }
}

// ---------------------------------------------------------------------------
extern "C" void kernel_launch(void* const* d_in, const int* in_sizes, int n_in,
                              void* d_out, int out_size, void* d_ws, size_t ws_size,
                              hipStream_t stream) {
  const float* X    = (const float*)d_in[0];  // [8,4096,2048]
  const float* W    = (const float*)d_in[1];  // [16,2048]
  const float* bias = (const float*)d_in[2];  // [16]
  float* out = (float*)d_out;                 // [8,4096,16] fp32

  k_switchgate<<<NBLK, 512, 0, stream>>>(X, W, bias, out);
}

// Round 8
// 57.537 us; speedup vs baseline: 1.2394x; 1.2394x over previous
//
#include <hip/hip_runtime.h>

typedef float f32x4 __attribute__((ext_vector_type(4)));

// Problem constants (fixed by reference setup_inputs)
constexpr int Bc = 8;
constexpr int Sc = 4096;
constexpr int Dc = 2048;
constexpr int Ec = 16;
constexpr int S_PER_BLK = 8;             // s-values per block
constexpr int TOK_PER_BLK = Bc * S_PER_BLK;  // 64 tokens (all 8 b's x 8 s)
constexpr int NBLK = Sc / S_PER_BLK;     // 512 blocks (2 per CU)
constexpr float EPS = 1e-6f;
constexpr float CAPACITY = 8.0f;         // int(1.0 * B)

// ---------------------------------------------------------------------------
// Fully fused SwitchGate kernel (one launch). [R5 structure — best verified]
//   Block owns s in [8*bid, 8*bid+8) for ALL 8 batch rows -> cross-B
//   denominator is block-local. Token-local index t = b*8 + s_loc.
//   Phase 1: 8 waves, wave w: D-quarter q=w>>1, expert octet g=w&1.
//     W slice in 64 VGPR/lane; X slice direct to VGPRs; depth-3 register
//     pipeline; value-merging butterfly (10 shfl / 8 experts);
//     partial logits -> padded LDS.
//   Phase 2: 8 thr/token: softmax + top-8 mask -> masked scores in LDS.
//   Phase 3: cross-B normalize, coalesced float2 stores to d_out.
// ---------------------------------------------------------------------------
__global__ __launch_bounds__(512, 4) void k_switchgate(
    const float* __restrict__ X, const float* __restrict__ W,
    const float* __restrict__ bias, float* __restrict__ out) {
  __shared__ float plds[4][TOK_PER_BLK][20];   // 20 KB partial logits
  __shared__ float masked[TOK_PER_BLK][18];    // 4.5 KB masked scores
  __shared__ float bias_lds[Ec];

  const int tid  = threadIdx.x;
  const int w    = tid >> 6;    // wave 0..7
  const int lane = tid & 63;
  const int q    = w >> 1;      // D-quarter 0..3
  const int g    = w & 1;       // expert octet
  const int eg0  = g * 8;

  if (tid < Ec) bias_lds[tid] = bias[tid];

  // W fragments: wreg[j][i] covers expert eg0+j, d = q*512 + i*256 + lane*4
  f32x4 wreg[8][2];
#pragma unroll
  for (int j = 0; j < 8; ++j) {
#pragma unroll
    for (int i = 0; i < 2; ++i) {
      wreg[j][i] = *reinterpret_cast<const f32x4*>(
          W + (size_t)(eg0 + j) * Dc + q * 512 + i * 256 + lane * 4);
    }
  }

  const int s0 = blockIdx.x * S_PER_BLK;
  const float* xbase = X + (size_t)s0 * Dc + q * 512 + lane * 4;

  f32x4 xa[2], xb[2], xc[2];

#define LOAD_BUF(buf, t)                                                      \
  {                                                                           \
    const float* p_ = xbase + (size_t)((t) >> 3) * (Sc * (size_t)Dc) +        \
                      (size_t)((t) & 7) * Dc;                                 \
    buf[0] = *reinterpret_cast<const f32x4*>(p_);                             \
    buf[1] = *reinterpret_cast<const f32x4*>(p_ + 256);                       \
  }

#define COMPUTE_STORE(buf, t)                                                 \
  {                                                                           \
    float a0 = 0.f, a1 = 0.f, a2 = 0.f, a3 = 0.f;                             \
    float a4 = 0.f, a5 = 0.f, a6 = 0.f, a7 = 0.f;                             \
    _Pragma("unroll") for (int i_ = 0; i_ < 2; ++i_) {                        \
      const f32x4 xv = buf[i_];                                               \
      _Pragma("unroll") for (int c_ = 0; c_ < 4; ++c_) {                      \
        a0 = fmaf(xv[c_], wreg[0][i_][c_], a0);                               \
        a1 = fmaf(xv[c_], wreg[1][i_][c_], a1);                               \
        a2 = fmaf(xv[c_], wreg[2][i_][c_], a2);                               \
        a3 = fmaf(xv[c_], wreg[3][i_][c_], a3);                               \
        a4 = fmaf(xv[c_], wreg[4][i_][c_], a4);                               \
        a5 = fmaf(xv[c_], wreg[5][i_][c_], a5);                               \
        a6 = fmaf(xv[c_], wreg[6][i_][c_], a6);                               \
        a7 = fmaf(xv[c_], wreg[7][i_][c_], a7);                               \
      }                                                                       \
    }                                                                         \
    /* value-merging butterfly: 10 shfl; lane l -> expert eg0+(l&7) */        \
    const bool o1 = (lane & 1) != 0;                                          \
    float b0, b1, b2, b3;                                                     \
    { float s_ = o1 ? a0 : a1; float r_ = __shfl_xor(s_, 1, 64);              \
      b0 = o1 ? (a1 + r_) : (a0 + r_); }                                      \
    { float s_ = o1 ? a2 : a3; float r_ = __shfl_xor(s_, 1, 64);              \
      b1 = o1 ? (a3 + r_) : (a2 + r_); }                                      \
    { float s_ = o1 ? a4 : a5; float r_ = __shfl_xor(s_, 1, 64);              \
      b2 = o1 ? (a5 + r_) : (a4 + r_); }                                      \
    { float s_ = o1 ? a6 : a7; float r_ = __shfl_xor(s_, 1, 64);              \
      b3 = o1 ? (a7 + r_) : (a6 + r_); }                                      \
    const bool o2 = (lane & 2) != 0;                                          \
    float c0, c1;                                                             \
    { float s_ = o2 ? b0 : b1; float r_ = __shfl_xor(s_, 2, 64);              \
      c0 = o2 ? (b1 + r_) : (b0 + r_); }                                      \
    { float s_ = o2 ? b2 : b3; float r_ = __shfl_xor(s_, 2, 64);              \
      c1 = o2 ? (b3 + r_) : (b2 + r_); }                                      \
    const bool o4 = (lane & 4) != 0;                                          \
    float dv;                                                                 \
    { float s_ = o4 ? c0 : c1; float r_ = __shfl_xor(s_, 4, 64);              \
      dv = o4 ? (c1 + r_) : (c0 + r_); }                                      \
    dv += __shfl_xor(dv, 8, 64);                                              \
    dv += __shfl_xor(dv, 16, 64);                                             \
    dv += __shfl_xor(dv, 32, 64);                                             \
    if (lane < 8) plds[q][t][eg0 + lane] = dv;                                \
  }

  // prologue: fill the 3-deep pipeline
  LOAD_BUF(xa, 0)
  LOAD_BUF(xb, 1)
  LOAD_BUF(xc, 2)

#pragma unroll 1
  for (int t = 0; t < TOK_PER_BLK - 6; t += 3) {
    COMPUTE_STORE(xa, t)
    LOAD_BUF(xa, t + 3)
    COMPUTE_STORE(xb, t + 1)
    LOAD_BUF(xb, t + 4)
    COMPUTE_STORE(xc, t + 2)
    LOAD_BUF(xc, t + 5)
  }
  // epilogue: tokens 60..63
  COMPUTE_STORE(xa, 60)
  LOAD_BUF(xa, 63)
  COMPUTE_STORE(xb, 61)
  COMPUTE_STORE(xc, 62)
  COMPUTE_STORE(xa, 63)

#undef LOAD_BUF
#undef COMPUTE_STORE

  __syncthreads();

  // ---- Phase 2: gate. 8 threads per token, each owns 2 experts. ----
  {
    const int t = tid >> 3;   // token-local 0..63 (= b*8 + s_loc)
    const int j = tid & 7;    // expert-pair index

    float l[16];
#pragma unroll
    for (int i = 0; i < 16; ++i) {
      l[i] = plds[0][t][i] + plds[1][t][i] + plds[2][t][i] + plds[3][t][i] +
             bias_lds[i];
    }

    float m = l[0];
#pragma unroll
    for (int i = 1; i < 16; ++i) m = fmaxf(m, l[i]);

    float ex[16];
    float Z = 0.f;
#pragma unroll
    for (int i = 0; i < 16; ++i) {
      ex[i] = __expf(l[i] - m);
      Z += ex[i];
    }
    const float invZ = 1.0f / Z;

    // top-8 mask via rank count (ties -> lower index, matches lax.top_k)
    const int i0 = 2 * j;
    int c0 = 0, c1 = 0;
#pragma unroll
    for (int k = 0; k < 16; ++k) {
      c0 += (l[k] > l[i0]) || ((l[k] == l[i0]) && (k < i0));
      c1 += (l[k] > l[i0 + 1]) || ((l[k] == l[i0 + 1]) && (k < i0 + 1));
    }
    float2 r;
    r.x = (c0 < 8) ? ex[i0] * invZ : 0.0f;
    r.y = (c1 < 8) ? ex[i0 + 1] * invZ : 0.0f;
    *reinterpret_cast<float2*>(&masked[t][i0]) = r;
  }

  __syncthreads();

  // ---- Phase 3: cross-B normalize + store. ----
  // thread tid = b*64 + s_loc*8 + j  (b = wave id -> coalesced 512B/wave)
  {
    const int b     = tid >> 6;
    const int s_loc = (tid >> 3) & 7;
    const int j     = tid & 7;
    const int i0    = 2 * j;

    float2 den = make_float2(EPS, EPS);
#pragma unroll
    for (int bp = 0; bp < 8; ++bp) {
      const float2 v = *reinterpret_cast<const float2*>(&masked[bp * 8 + s_loc][i0]);
      den.x += v.x;
      den.y += v.y;
    }
    const float2 mv = *reinterpret_cast<const float2*>(&masked[b * 8 + s_loc][i0]);
    float2 r;
    r.x = mv.x * CAPACITY / den.x;
    r.y = mv.y * CAPACITY / den.y;
    *reinterpret_cast<float2*>(
        out + ((size_t)b * Sc + s0 + s_loc) * Ec + i0) = r;
  }
}

// ---------------------------------------------------------------------------
extern "C" void kernel_launch(void* const* d_in, const int* in_sizes, int n_in,
                              void* d_out, int out_size, void* d_ws, size_t ws_size,
                              hipStream_t stream) {
  const float* X    = (const float*)d_in[0];  // [8,4096,2048]
  const float* W    = (const float*)d_in[1];  // [16,2048]
  const float* bias = (const float*)d_in[2];  // [16]
  float* out = (float*)d_out;                 // [8,4096,16] fp32

  k_switchgate<<<NBLK, 512, 0, stream>>>(X, W, bias, out);
}

// Round 9
// 56.863 us; speedup vs baseline: 1.2541x; 1.0119x over previous
//
#include <hip/hip_runtime.h>

typedef float f32x4 __attribute__((ext_vector_type(4)));

// Problem constants (fixed by reference setup_inputs)
constexpr int Bc = 8;
constexpr int Sc = 4096;
constexpr int Dc = 2048;
constexpr int Ec = 16;
constexpr int S_PER_BLK = 8;             // s-values per block
constexpr int TOK_PER_BLK = Bc * S_PER_BLK;  // 64 tokens (all 8 b's x 8 s)
constexpr int NBLK = Sc / S_PER_BLK;     // 512 blocks (2 per CU)
constexpr float EPS = 1e-6f;
constexpr float CAPACITY = 8.0f;         // int(1.0 * B)

// ---------------------------------------------------------------------------
// Fully fused SwitchGate kernel (one launch). [R5 structure + DEPTH-4 probe]
//   Block owns s in [8*bid, 8*bid+8) for ALL 8 batch rows -> cross-B
//   denominator is block-local. Token-local index t = b*8 + s_loc.
//   Phase 1: 8 waves, wave w: D-quarter q=w>>1, expert octet g=w&1.
//     W slice in 64 VGPR/lane; X slice direct to VGPRs; depth-4 register
//     pipeline (single isolated change vs R5's depth-3); value-merging
//     butterfly (10 shfl / 8 experts); partial logits -> padded LDS.
//   Phase 2: 8 thr/token: softmax + top-8 mask -> masked scores in LDS.
//   Phase 3: cross-B normalize, coalesced float2 stores to d_out.
// ---------------------------------------------------------------------------
__global__ __launch_bounds__(512, 4) void k_switchgate(
    const float* __restrict__ X, const float* __restrict__ W,
    const float* __restrict__ bias, float* __restrict__ out) {
  __shared__ float plds[4][TOK_PER_BLK][20];   // 20 KB partial logits
  __shared__ float masked[TOK_PER_BLK][18];    // 4.5 KB masked scores
  __shared__ float bias_lds[Ec];

  const int tid  = threadIdx.x;
  const int w    = tid >> 6;    // wave 0..7
  const int lane = tid & 63;
  const int q    = w >> 1;      // D-quarter 0..3
  const int g    = w & 1;       // expert octet
  const int eg0  = g * 8;

  if (tid < Ec) bias_lds[tid] = bias[tid];

  // W fragments: wreg[j][i] covers expert eg0+j, d = q*512 + i*256 + lane*4
  f32x4 wreg[8][2];
#pragma unroll
  for (int j = 0; j < 8; ++j) {
#pragma unroll
    for (int i = 0; i < 2; ++i) {
      wreg[j][i] = *reinterpret_cast<const f32x4*>(
          W + (size_t)(eg0 + j) * Dc + q * 512 + i * 256 + lane * 4);
    }
  }

  const int s0 = blockIdx.x * S_PER_BLK;
  const float* xbase = X + (size_t)s0 * Dc + q * 512 + lane * 4;

  f32x4 xa[2], xb[2], xc[2], xd[2];

#define LOAD_BUF(buf, t)                                                      \
  {                                                                           \
    const float* p_ = xbase + (size_t)((t) >> 3) * (Sc * (size_t)Dc) +        \
                      (size_t)((t) & 7) * Dc;                                 \
    buf[0] = *reinterpret_cast<const f32x4*>(p_);                             \
    buf[1] = *reinterpret_cast<const f32x4*>(p_ + 256);                       \
  }

#define COMPUTE_STORE(buf, t)                                                 \
  {                                                                           \
    float a0 = 0.f, a1 = 0.f, a2 = 0.f, a3 = 0.f;                             \
    float a4 = 0.f, a5 = 0.f, a6 = 0.f, a7 = 0.f;                             \
    _Pragma("unroll") for (int i_ = 0; i_ < 2; ++i_) {                        \
      const f32x4 xv = buf[i_];                                               \
      _Pragma("unroll") for (int c_ = 0; c_ < 4; ++c_) {                      \
        a0 = fmaf(xv[c_], wreg[0][i_][c_], a0);                               \
        a1 = fmaf(xv[c_], wreg[1][i_][c_], a1);                               \
        a2 = fmaf(xv[c_], wreg[2][i_][c_], a2);                               \
        a3 = fmaf(xv[c_], wreg[3][i_][c_], a3);                               \
        a4 = fmaf(xv[c_], wreg[4][i_][c_], a4);                               \
        a5 = fmaf(xv[c_], wreg[5][i_][c_], a5);                               \
        a6 = fmaf(xv[c_], wreg[6][i_][c_], a6);                               \
        a7 = fmaf(xv[c_], wreg[7][i_][c_], a7);                               \
      }                                                                       \
    }                                                                         \
    /* value-merging butterfly: 10 shfl; lane l -> expert eg0+(l&7) */        \
    const bool o1 = (lane & 1) != 0;                                          \
    float b0, b1, b2, b3;                                                     \
    { float s_ = o1 ? a0 : a1; float r_ = __shfl_xor(s_, 1, 64);              \
      b0 = o1 ? (a1 + r_) : (a0 + r_); }                                      \
    { float s_ = o1 ? a2 : a3; float r_ = __shfl_xor(s_, 1, 64);              \
      b1 = o1 ? (a3 + r_) : (a2 + r_); }                                      \
    { float s_ = o1 ? a4 : a5; float r_ = __shfl_xor(s_, 1, 64);              \
      b2 = o1 ? (a5 + r_) : (a4 + r_); }                                      \
    { float s_ = o1 ? a6 : a7; float r_ = __shfl_xor(s_, 1, 64);              \
      b3 = o1 ? (a7 + r_) : (a6 + r_); }                                      \
    const bool o2 = (lane & 2) != 0;                                          \
    float c0, c1;                                                             \
    { float s_ = o2 ? b0 : b1; float r_ = __shfl_xor(s_, 2, 64);              \
      c0 = o2 ? (b1 + r_) : (b0 + r_); }                                      \
    { float s_ = o2 ? b2 : b3; float r_ = __shfl_xor(s_, 2, 64);              \
      c1 = o2 ? (b3 + r_) : (b2 + r_); }                                      \
    const bool o4 = (lane & 4) != 0;                                          \
    float dv;                                                                 \
    { float s_ = o4 ? c0 : c1; float r_ = __shfl_xor(s_, 4, 64);              \
      dv = o4 ? (c1 + r_) : (c0 + r_); }                                      \
    dv += __shfl_xor(dv, 8, 64);                                              \
    dv += __shfl_xor(dv, 16, 64);                                             \
    dv += __shfl_xor(dv, 32, 64);                                             \
    if (lane < 8) plds[q][t][eg0 + lane] = dv;                                \
  }

  // prologue: fill the 4-deep pipeline
  LOAD_BUF(xa, 0)
  LOAD_BUF(xb, 1)
  LOAD_BUF(xc, 2)
  LOAD_BUF(xd, 3)

#pragma unroll 1
  for (int t = 0; t < TOK_PER_BLK - 8; t += 4) {
    COMPUTE_STORE(xa, t)
    LOAD_BUF(xa, t + 4)
    COMPUTE_STORE(xb, t + 1)
    LOAD_BUF(xb, t + 5)
    COMPUTE_STORE(xc, t + 2)
    LOAD_BUF(xc, t + 6)
    COMPUTE_STORE(xd, t + 3)
    LOAD_BUF(xd, t + 7)
  }
  // epilogue: tokens 56..63
  COMPUTE_STORE(xa, 56)
  LOAD_BUF(xa, 60)
  COMPUTE_STORE(xb, 57)
  LOAD_BUF(xb, 61)
  COMPUTE_STORE(xc, 58)
  LOAD_BUF(xc, 62)
  COMPUTE_STORE(xd, 59)
  LOAD_BUF(xd, 63)
  COMPUTE_STORE(xa, 60)
  COMPUTE_STORE(xb, 61)
  COMPUTE_STORE(xc, 62)
  COMPUTE_STORE(xd, 63)

#undef LOAD_BUF
#undef COMPUTE_STORE

  __syncthreads();

  // ---- Phase 2: gate. 8 threads per token, each owns 2 experts. ----
  {
    const int t = tid >> 3;   // token-local 0..63 (= b*8 + s_loc)
    const int j = tid & 7;    // expert-pair index

    float l[16];
#pragma unroll
    for (int i = 0; i < 16; ++i) {
      l[i] = plds[0][t][i] + plds[1][t][i] + plds[2][t][i] + plds[3][t][i] +
             bias_lds[i];
    }

    float m = l[0];
#pragma unroll
    for (int i = 1; i < 16; ++i) m = fmaxf(m, l[i]);

    float ex[16];
    float Z = 0.f;
#pragma unroll
    for (int i = 0; i < 16; ++i) {
      ex[i] = __expf(l[i] - m);
      Z += ex[i];
    }
    const float invZ = 1.0f / Z;

    // top-8 mask via rank count (ties -> lower index, matches lax.top_k)
    const int i0 = 2 * j;
    int c0 = 0, c1 = 0;
#pragma unroll
    for (int k = 0; k < 16; ++k) {
      c0 += (l[k] > l[i0]) || ((l[k] == l[i0]) && (k < i0));
      c1 += (l[k] > l[i0 + 1]) || ((l[k] == l[i0 + 1]) && (k < i0 + 1));
    }
    float2 r;
    r.x = (c0 < 8) ? ex[i0] * invZ : 0.0f;
    r.y = (c1 < 8) ? ex[i0 + 1] * invZ : 0.0f;
    *reinterpret_cast<float2*>(&masked[t][i0]) = r;
  }

  __syncthreads();

  // ---- Phase 3: cross-B normalize + store. ----
  // thread tid = b*64 + s_loc*8 + j  (b = wave id -> coalesced 512B/wave)
  {
    const int b     = tid >> 6;
    const int s_loc = (tid >> 3) & 7;
    const int j     = tid & 7;
    const int i0    = 2 * j;

    float2 den = make_float2(EPS, EPS);
#pragma unroll
    for (int bp = 0; bp < 8; ++bp) {
      const float2 v = *reinterpret_cast<const float2*>(&masked[bp * 8 + s_loc][i0]);
      den.x += v.x;
      den.y += v.y;
    }
    const float2 mv = *reinterpret_cast<const float2*>(&masked[b * 8 + s_loc][i0]);
    float2 r;
    r.x = mv.x * CAPACITY / den.x;
    r.y = mv.y * CAPACITY / den.y;
    *reinterpret_cast<float2*>(
        out + ((size_t)b * Sc + s0 + s_loc) * Ec + i0) = r;
  }
}

// ---------------------------------------------------------------------------
extern "C" void kernel_launch(void* const* d_in, const int* in_sizes, int n_in,
                              void* d_out, int out_size, void* d_ws, size_t ws_size,
                              hipStream_t stream) {
  const float* X    = (const float*)d_in[0];  // [8,4096,2048]
  const float* W    = (const float*)d_in[1];  // [16,2048]
  const float* bias = (const float*)d_in[2];  // [16]
  float* out = (float*)d_out;                 // [8,4096,16] fp32

  k_switchgate<<<NBLK, 512, 0, stream>>>(X, W, bias, out);
}